// Round 10
// baseline (136.972 us; speedup 1.0000x reference)
//
#include <hip/hip_runtime.h>
#include <hip/hip_bf16.h>

// out[b,s,h] = sum_{a,d} x[b,a,h,d] * K[s,a] * W[s,d]
// bf16 GEMM: out[(b,h), s] = X[(b,h),(a,d)] . Wm[s,(a,d)]^T
//   M = B*H = 196608, K = 112 -> padded 128 (exact zeros in Wm), N = S = 512
//
// Round-10: NO A-STAGING. Each lane builds its MFMA A-fragment directly from
// global: fragment k-slice (ks*32+kq*8..+7) == x[b, a=ks*4+kq, h, 0..7] =
// 32 contiguous bytes -> two float4 loads + 2 packed f32->bf16 cvt.
//  - no LDS A-tile, no staging pass, NO __syncthreads at all.
//  - block x-region (43KB) is L2-hot for the 4x sblk re-reads.
//  - k=112..127: Wm rows are exact zeros, so A only needs to be FINITE;
//    clamp a->13 for the 2 tail lanes (in-bounds garbage * 0 = 0).
//  - epilogue identical to round 5 (best, 124.8us): wave-private 6KB LDS
//    transpose -> coalesced float4 stores; per-wave sblk stagger kept.
//  LDS = 8 x 6KB = 48KB (epilogue only).

#define A_DIM 14
#define H_DIM 3
#define D_DIM 8
#define S_DIM 512
#define KP    128
#define XSTR  (A_DIM * H_DIM * D_DIM)   // 336 floats per batch
#define XBYT  (XSTR * 4)                // 1344 bytes per batch
#define OSTR  (S_DIM * H_DIM)           // 1536 floats per batch

#define BB 32                 // batches per block
#define BN 128                // spots per s-block
#define EP_CHUNK 6144         // per-wave: 16 batches * 32 s * 3 h * 4B
#define LDS_BYTES (8 * EP_CHUNK)   // 49152 B

typedef short bf16x8 __attribute__((ext_vector_type(8)));
typedef float f32x4  __attribute__((ext_vector_type(4)));

static __device__ __forceinline__ unsigned f2bf(float f) {
    unsigned u = __float_as_uint(f);
    u += 0x7FFFu + ((u >> 16) & 1u);
    return u >> 16;
}

// pack two f32 -> one dword of two RNE bf16 (lo = first)
static __device__ __forceinline__ unsigned pk2(float lo, float hi) {
    __hip_bfloat162 t = __float22bfloat162_rn(make_float2(lo, hi));
    return *reinterpret_cast<unsigned*>(&t);
}

// ---------- build Wm[s][k] bf16, k = a*8+d, zero-padded to KP ----------
__global__ __launch_bounds__(S_DIM) void build_wm_kernel(
    const float* __restrict__ windWeights,   // (S, D)
    const float* __restrict__ alt,           // (S, 1)
    unsigned short* __restrict__ wmg)        // (S, KP) bf16 bits
{
    const int s = threadIdx.x;
    const float av = alt[s];
    float w[D_DIM];
#pragma unroll
    for (int d = 0; d < D_DIM; ++d) w[d] = windWeights[s * D_DIM + d];
#pragma unroll
    for (int a = 0; a < A_DIM; ++a) {
        const float g  = (float)a - av;
        const float t1 = fminf(fmaxf(g + 1.0f, 0.0f), 1.0f);
        const float t0 = fminf(fmaxf(g,        0.0f), 1.0f);
        const float Ka = t1 - t0;   // exact reference clip form
#pragma unroll
        for (int d = 0; d < D_DIM; ++d)
            wmg[s * KP + a * D_DIM + d] = (unsigned short)f2bf(Ka * w[d]);
    }
#pragma unroll
    for (int k = A_DIM * D_DIM; k < KP; ++k) wmg[s * KP + k] = 0;
}

// ---------- main GEMM ----------
__global__ __launch_bounds__(512, 4) void wind_gemm_kernel(
    const float* __restrict__ x,             // (B, A, H, D) fp32
    const unsigned short* __restrict__ wmg,  // (S, KP) bf16
    float* __restrict__ out)                 // (B, S, H) fp32
{
    __shared__ __align__(16) char lds[LDS_BYTES];

    const int tid = threadIdx.x;
    const int b0  = blockIdx.x * BB;

    const int lane = tid & 63;
    const int wid  = tid >> 6;
    const int wm_  = wid >> 2;           // 0..1
    const int ws_  = wid & 3;            // 0..3
    const int r    = lane & 15;
    const int kq   = lane >> 4;          // 0..3
    const int r12  = r * 12;

    // per-lane A base addresses for the 3 m-fragments (row m = wm*48 + i*16 + r)
    const char* xb = (const char*)x;
    const char* abase[3];
#pragma unroll
    for (int i = 0; i < 3; ++i) {
        const int m  = wm_ * 48 + i * 16 + r;
        const int bl = (unsigned)m / 3u;
        const int hh = m - bl * 3;
        abase[i] = xb + (size_t)(b0 + bl) * XBYT + hh * 32;
    }
    // per-lane a-offsets per ks (a = ks*4+kq, clamped to 13 for the zero-B tail)
    int aoff[4];
#pragma unroll
    for (int ks = 0; ks < 4; ++ks) {
        int a_ = ks * 4 + kq;
        if (a_ > A_DIM - 1) a_ = A_DIM - 1;   // finite garbage * zero-B = 0
        aoff[ks] = a_ * (H_DIM * D_DIM * 4);  // a * 96 bytes
    }

    char* ep = lds + wid * EP_CHUNK;

#pragma unroll 1
    for (int k = 0; k < 4; ++k) {
        const int sblk = (k + wid + blockIdx.x) & 3;   // per-wave stagger
        const int s0 = sblk * BN;

        // B frags direct from global (L2-hot)
        const char* wb = (const char*)wmg + (size_t)(s0 + ws_ * 32 + r) * 256 + kq * 16;
        bf16x8 bfr[4][2];
#pragma unroll
        for (int ks = 0; ks < 4; ++ks)
#pragma unroll
            for (int j = 0; j < 2; ++j)
                bfr[ks][j] = *reinterpret_cast<const bf16x8*>(wb + j * 16 * 256 + ks * 64);

        f32x4 acc[3][2];
#pragma unroll
        for (int i = 0; i < 3; ++i)
#pragma unroll
            for (int j = 0; j < 2; ++j) {
                f32x4 z = {0.f, 0.f, 0.f, 0.f};
                acc[i][j] = z;
            }

#pragma unroll
        for (int ks = 0; ks < 4; ++ks) {
#pragma unroll
            for (int i = 0; i < 3; ++i) {
                const float4 v0 = *reinterpret_cast<const float4*>(abase[i] + aoff[ks]);
                const float4 v1 = *reinterpret_cast<const float4*>(abase[i] + aoff[ks] + 16);
                union { bf16x8 v; unsigned u[4]; } c;
                c.u[0] = pk2(v0.x, v0.y);
                c.u[1] = pk2(v0.z, v0.w);
                c.u[2] = pk2(v1.x, v1.y);
                c.u[3] = pk2(v1.z, v1.w);
                acc[i][0] = __builtin_amdgcn_mfma_f32_16x16x32_bf16(c.v, bfr[ks][0], acc[i][0], 0, 0, 0);
                acc[i][1] = __builtin_amdgcn_mfma_f32_16x16x32_bf16(c.v, bfr[ks][1], acc[i][1], 0, 0, 0);
            }
        }

        // ---- epilogue: acc -> wave-private LDS chunk in out-layout (R5) ----
        // chunk layout: [b_in(16)][soff(32)][h(3)] floats; addr = b_in*384 + soff*12 + h*4
        // j=0 at soff=r, j=1 at soff=r+16 (+192B) -> compiler fuses to ds_write2
#pragma unroll
        for (int i = 0; i < 3; ++i) {
            const int m_in0 = i * 16 + kq * 4;   // m within wave tile (48 rows)
            int b_in = (unsigned)m_in0 / 3u;
            int h    = m_in0 - b_in * 3;
#pragma unroll
            for (int reg = 0; reg < 4; ++reg) {
                const int bh = b_in * 384 + h * 4;
                *reinterpret_cast<float*>(ep + bh + r12)       = acc[i][0][reg];
                *reinterpret_cast<float*>(ep + bh + r12 + 192) = acc[i][1][reg];
                ++h;
                if (h == 3) { h = 0; ++b_in; }
            }
        }
        asm volatile("s_waitcnt lgkmcnt(0)" ::: "memory");

        // ---- readback + fully coalesced float4 stores ----
        const size_t obase = (size_t)(b0 + wm_ * 16) * OSTR + (size_t)(s0 + ws_ * 32) * 3;
#pragma unroll
        for (int t = 0; t < 6; ++t) {
            const unsigned u    = (unsigned)lane + t * 64u;  // float4 index, < 384
            const unsigned b_in = u / 24u;                   // 24 float4 per batch
            const unsigned rem  = u - b_in * 24u;
            const float4 v = *reinterpret_cast<const float4*>(ep + u * 16u);
            *reinterpret_cast<float4*>(out + obase + (size_t)b_in * OSTR + rem * 4u) = v;
        }
        asm volatile("" ::: "memory");   // keep next sblk's LDS writes after these reads
    }
}

extern "C" void kernel_launch(void* const* d_in, const int* in_sizes, int n_in,
                              void* d_out, int out_size, void* d_ws, size_t ws_size,
                              hipStream_t stream) {
    const float* x           = (const float*)d_in[0];
    const float* windWeights = (const float*)d_in[1];
    const float* alt         = (const float*)d_in[2];
    float* out = (float*)d_out;

    const int Btot = in_sizes[0] / XSTR;     // 65536

    unsigned short* wmg = (unsigned short*)d_ws;   // S_DIM * KP * 2 = 128 KB

    build_wm_kernel<<<1, S_DIM, 0, stream>>>(windWeights, alt, wmg);

    const int blocks = Btot / BB;                  // 2048
    wind_gemm_kernel<<<blocks, 512, 0, stream>>>(x, wmg, out);
}

// Round 12
// 95.617 us; speedup vs baseline: 1.4325x; 1.4325x over previous
//
#include <hip/hip_runtime.h>

// out[b,s,h] = sum_{a,d} x[b,a,h,d] * K[s,a] * W[s,d]
// bf16 GEMM: out[(b,h), s] = X[(b,h),(a,d)] . Wm[s,(a,d)]^T
//   M = B*H = 196608, K = 112 -> padded 128 (exact zeros), N = S = 512
//
// Round-12 = round-11 with the compile fix: __builtin_nontemporal_store needs
// a clang ext_vector_type pointer, not HIP's float4 class. Theory unchanged:
//  - out is write-once streaming (402 MB/iter > 256 MB L3). nt stores skip
//    cache allocation -> x (88 MB) stays L3-resident; no allocate/evict churn.
//  - everything else byte-identical to round 5 (best, 124.8us).
//  LDS = 24KB (A) + 48KB (ep) = 72KB -> 2 blocks/CU.

#define A_DIM 14
#define H_DIM 3
#define D_DIM 8
#define S_DIM 512
#define KP    128
#define XSTR  (A_DIM * H_DIM * D_DIM)   // 336 floats per batch
#define OSTR  (S_DIM * H_DIM)           // 1536 floats per batch

#define BB 32                 // batches per block
#define BM 96                 // m rows per block
#define BN 128                // spots per s-block
#define A_LDS (BM * 256)      // 24576 B
#define EP_CHUNK 6144         // per-wave: 16 batches * 32 s * 3 h * 4B
#define LDS_BYTES (A_LDS + 8 * EP_CHUNK)   // 73728 B

typedef short bf16x8 __attribute__((ext_vector_type(8)));
typedef float f32x4  __attribute__((ext_vector_type(4)));

static __device__ __forceinline__ unsigned f2bf(float f) {
    unsigned u = __float_as_uint(f);
    u += 0x7FFFu + ((u >> 16) & 1u);
    return u >> 16;
}

// ---------- build Wm[s][k] bf16, k = a*8+d, zero-padded to KP ----------
__global__ __launch_bounds__(S_DIM) void build_wm_kernel(
    const float* __restrict__ windWeights,   // (S, D)
    const float* __restrict__ alt,           // (S, 1)
    unsigned short* __restrict__ wmg)        // (S, KP) bf16 bits
{
    const int s = threadIdx.x;
    const float av = alt[s];
    float w[D_DIM];
#pragma unroll
    for (int d = 0; d < D_DIM; ++d) w[d] = windWeights[s * D_DIM + d];
#pragma unroll
    for (int a = 0; a < A_DIM; ++a) {
        const float g  = (float)a - av;
        const float t1 = fminf(fmaxf(g + 1.0f, 0.0f), 1.0f);
        const float t0 = fminf(fmaxf(g,        0.0f), 1.0f);
        const float Ka = t1 - t0;   // exact reference clip form
#pragma unroll
        for (int d = 0; d < D_DIM; ++d)
            wmg[s * KP + a * D_DIM + d] = (unsigned short)f2bf(Ka * w[d]);
    }
#pragma unroll
    for (int k = A_DIM * D_DIM; k < KP; ++k) wmg[s * KP + k] = 0;
}

// ---------- main GEMM ----------
__global__ __launch_bounds__(512, 4) void wind_gemm_kernel(
    const float* __restrict__ x,             // (B, A, H, D) fp32
    const unsigned short* __restrict__ wmg,  // (S, KP) bf16
    float* __restrict__ out)                 // (B, S, H) fp32
{
    __shared__ __align__(16) char lds[LDS_BYTES];

    const int tid = threadIdx.x;
    const int b0  = blockIdx.x * BB;

    // ---- stage A: x[b0..b0+31] fp32 -> bf16 LDS [m=96][256B], swizzled ----
    const float* xg = x + (size_t)b0 * XSTR;
#pragma unroll
    for (int it = 0; it < 6; ++it) {
        const int q = tid + it * 512;          // float4 id; 84 per batch, 2688 total
        if (q < 84 * BB) {
            const int b_loc = q / 84;
            const int o   = q - b_loc * 84;
            const int of  = o * 4;             // float offset within batch
            const int a   = of / 24;
            const int r24 = of - a * 24;
            const int h   = r24 >> 3;
            const int d0  = r24 & 7;           // 0 or 4
            const float4 v = *reinterpret_cast<const float4*>(xg + (size_t)b_loc * XSTR + of);
            const unsigned lo = f2bf(v.x) | (f2bf(v.y) << 16);
            const unsigned hi = f2bf(v.z) | (f2bf(v.w) << 16);
            const int m = b_loc * 3 + h;
            int byte = m * 256 + a * 16 + d0 * 2;
            byte ^= (m & 7) << 4;
            *reinterpret_cast<uint2*>(lds + byte) = make_uint2(lo, hi);
        }
    }
    // zero-pad k = 112..127 (32 B per row as 4 x uint2; 384 writes)
    if (tid < BM * 4) {
        const int m = tid >> 2;
        const int c = tid & 3;
        int byte = m * 256 + 224 + c * 8;
        byte ^= (m & 7) << 4;
        *reinterpret_cast<uint2*>(lds + byte) = make_uint2(0u, 0u);
    }
    __syncthreads();

    // ---- wave decomposition: 8 waves = 2 m x 4 s; wave tile 48m x 32s ----
    const int lane = tid & 63;
    const int wid  = tid >> 6;
    const int wm_  = wid >> 2;           // 0..1
    const int ws_  = wid & 3;            // 0..3
    const int r    = lane & 15;
    const int kq   = lane >> 4;          // 0..3
    const int swz  = (r & 7) << 4;
    const int r12  = r * 12;

    const int abase = (wm_ * 48 + r) * 256 + kq * 16;
    char* ep = lds + A_LDS + wid * EP_CHUNK;

#pragma unroll 1
    for (int k = 0; k < 4; ++k) {
        const int sblk = (k + wid + blockIdx.x) & 3;   // per-wave stagger
        const int s0 = sblk * BN;

        // B frags direct from global (L2-hot); rows s0+ws*32+r (+j*16), k-slice kq*16+ks*64
        const char* wb = (const char*)wmg + (size_t)(s0 + ws_ * 32 + r) * 256 + kq * 16;
        bf16x8 bfr[4][2];
#pragma unroll
        for (int ks = 0; ks < 4; ++ks)
#pragma unroll
            for (int j = 0; j < 2; ++j)
                bfr[ks][j] = *reinterpret_cast<const bf16x8*>(wb + j * 16 * 256 + ks * 64);

        f32x4 acc[3][2];
#pragma unroll
        for (int i = 0; i < 3; ++i)
#pragma unroll
            for (int j = 0; j < 2; ++j) {
                f32x4 z = {0.f, 0.f, 0.f, 0.f};
                acc[i][j] = z;
            }

#pragma unroll
        for (int ks = 0; ks < 4; ++ks) {
            bf16x8 af[3];
#pragma unroll
            for (int i = 0; i < 3; ++i)
                af[i] = *reinterpret_cast<bf16x8*>(lds + ((abase + i * 16 * 256 + ks * 64) ^ swz));
#pragma unroll
            for (int i = 0; i < 3; ++i)
#pragma unroll
                for (int j = 0; j < 2; ++j)
                    acc[i][j] = __builtin_amdgcn_mfma_f32_16x16x32_bf16(af[i], bfr[ks][j], acc[i][j], 0, 0, 0);
        }

        // ---- epilogue: acc -> wave-private LDS chunk in out-layout ----
        // chunk layout: [b_in (16)][soff (32)][h (3)] floats; addr = b_in*384 + soff*12 + h*4
#pragma unroll
        for (int i = 0; i < 3; ++i) {
            const int m_in0 = i * 16 + kq * 4;   // m within wave tile (48 rows)
            int b_in = (unsigned)m_in0 / 3u;
            int h    = m_in0 - b_in * 3;
#pragma unroll
            for (int reg = 0; reg < 4; ++reg) {
                const int bh = b_in * 384 + h * 4;
                *reinterpret_cast<float*>(ep + bh + r12)       = acc[i][0][reg];
                *reinterpret_cast<float*>(ep + bh + r12 + 192) = acc[i][1][reg];
                ++h;
                if (h == 3) { h = 0; ++b_in; }
            }
        }
        asm volatile("s_waitcnt lgkmcnt(0)" ::: "memory");

        // ---- readback + fully coalesced NON-TEMPORAL float4 stores ----
        // wave region: batches [b0 + wm*16, +16), out floats [ (s0+ws*32)*3, +96 ) per batch
        const size_t obase = (size_t)(b0 + wm_ * 16) * OSTR + (size_t)(s0 + ws_ * 32) * 3;
#pragma unroll
        for (int t = 0; t < 6; ++t) {
            const unsigned u    = (unsigned)lane + t * 64u;  // float4 index, < 384
            const unsigned b_in = u / 24u;                   // 24 float4 per batch
            const unsigned rem  = u - b_in * 24u;
            const f32x4 v = *reinterpret_cast<const f32x4*>(ep + u * 16u);
            __builtin_nontemporal_store(
                v, reinterpret_cast<f32x4*>(out + obase + (size_t)b_in * OSTR + rem * 4u));
        }
        asm volatile("" ::: "memory");   // keep next sblk's LDS writes after these reads
    }
}

extern "C" void kernel_launch(void* const* d_in, const int* in_sizes, int n_in,
                              void* d_out, int out_size, void* d_ws, size_t ws_size,
                              hipStream_t stream) {
    const float* x           = (const float*)d_in[0];
    const float* windWeights = (const float*)d_in[1];
    const float* alt         = (const float*)d_in[2];
    float* out = (float*)d_out;

    const int Btot = in_sizes[0] / XSTR;     // 65536

    unsigned short* wmg = (unsigned short*)d_ws;   // S_DIM * KP * 2 = 128 KB

    build_wm_kernel<<<1, S_DIM, 0, stream>>>(windWeights, alt, wmg);

    const int blocks = Btot / BB;                  // 2048
    wind_gemm_kernel<<<blocks, 512, 0, stream>>>(x, wmg, out);
}